// Round 1
// baseline (106.900 us; speedup 1.0000x reference)
//
#include <hip/hip_runtime.h>

constexpr int BSZ = 512;
constexpr int DIM = 128;
#define MARGIN_F 0.2f
#define EPS_F 1e-6f

// One block per anchor i. Computes the distance row D[i,:] on the fly,
// compacts positives/negatives into dense LDS arrays, then does the
// O(nP*nN) relu-sum with wave-strided positives / lane-strided negatives.
__global__ __launch_bounds__(256) void triplet_main(
    const float* __restrict__ feat, const int* __restrict__ mask,
    double* __restrict__ num_part, int* __restrict__ den_part) {
  const int i = blockIdx.x;
  const int tid = threadIdx.x;

  __shared__ float fi[DIM];
  __shared__ float apos[BSZ];   // distances to positives (compacted)
  __shared__ float bneg[BSZ];   // distances to negatives (compacted)
  __shared__ int cnt[2];
  __shared__ float wred[4];

  if (tid < 2) cnt[tid] = 0;
  if (tid < DIM / 4) {
    const float4 v = ((const float4*)(feat + (long)i * DIM))[tid];
    fi[tid * 4 + 0] = v.x; fi[tid * 4 + 1] = v.y;
    fi[tid * 4 + 2] = v.z; fi[tid * 4 + 3] = v.w;
  }
  __syncthreads();

  // Distance row + compaction. 2 columns per thread.
  for (int k = tid; k < BSZ; k += 256) {
    const float4* fk = (const float4*)(feat + (long)k * DIM);
    float s = 0.f;
#pragma unroll
    for (int d = 0; d < DIM / 4; ++d) {
      float4 v = fk[d];
      float x0 = fi[4 * d + 0] - v.x + EPS_F;
      float x1 = fi[4 * d + 1] - v.y + EPS_F;
      float x2 = fi[4 * d + 2] - v.z + EPS_F;
      float x3 = fi[4 * d + 3] - v.w + EPS_F;
      s = fmaf(x0, x0, s); s = fmaf(x1, x1, s);
      s = fmaf(x2, x2, s); s = fmaf(x3, x3, s);
    }
    const float dist = sqrtf(s);
    const int m = mask[(long)i * BSZ + k];
    if (m != 0) {
      apos[atomicAdd(&cnt[0], 1)] = dist;          // pos includes diagonal if mask[i,i]==1
    } else if (k != i) {
      bneg[atomicAdd(&cnt[1], 1)] = dist;          // neg excludes diagonal
    }
  }
  __syncthreads();

  const int nP = cnt[0];
  const int nN = cnt[1];
  const int nNpad = (nN + 63) & ~63;               // pad to wave multiple
  {
    const int k = nN + tid;
    if (k < nNpad) bneg[k] = 1e30f;                // relu(aj - 1e30) == 0
  }
  __syncthreads();

  // Triplet reduction: wave-strided j (broadcast apos[j]), lane-strided k.
  const int wave = tid >> 6;
  const int lane = tid & 63;
  float lsum = 0.f;
  for (int j = wave; j < nP; j += 4) {
    const float aj = apos[j] + MARGIN_F;
    for (int k = lane; k < nNpad; k += 64) {
      lsum += fmaxf(aj - bneg[k], 0.f);
    }
  }

  // Block reduction: shuffle within wave, LDS across waves.
  for (int off = 32; off > 0; off >>= 1)
    lsum += __shfl_down(lsum, off, 64);
  if ((tid & 63) == 0) wred[tid >> 6] = lsum;
  __syncthreads();
  if (tid == 0) {
    num_part[i] = (double)(wred[0] + wred[1] + wred[2] + wred[3]);
    den_part[i] = nP * nN;
  }
}

__global__ __launch_bounds__(256) void triplet_finalize(
    const double* __restrict__ num_part, const int* __restrict__ den_part,
    float* __restrict__ out) {
  const int tid = threadIdx.x;
  double n = 0.0;
  long long d = 0;
  for (int i = tid; i < BSZ; i += 256) {
    n += num_part[i];
    d += den_part[i];
  }
  __shared__ double sn[4];
  __shared__ long long sd[4];
  for (int off = 32; off > 0; off >>= 1) {
    n += __shfl_down(n, off, 64);
    d += __shfl_down(d, off, 64);
  }
  if ((tid & 63) == 0) { sn[tid >> 6] = n; sd[tid >> 6] = d; }
  __syncthreads();
  if (tid == 0) {
    const double N = sn[0] + sn[1] + sn[2] + sn[3];
    const long long Dn = sd[0] + sd[1] + sd[2] + sd[3];
    out[0] = (Dn > 0) ? (float)(N / (double)Dn) : 0.0f;
  }
}

extern "C" void kernel_launch(void* const* d_in, const int* in_sizes, int n_in,
                              void* d_out, int out_size, void* d_ws, size_t ws_size,
                              hipStream_t stream) {
  const float* feat = (const float*)d_in[0];
  const int* mask = (const int*)d_in[1];
  float* out = (float*)d_out;

  double* num_part = (double*)d_ws;
  int* den_part = (int*)((char*)d_ws + BSZ * sizeof(double));

  triplet_main<<<BSZ, 256, 0, stream>>>(feat, mask, num_part, den_part);
  triplet_finalize<<<1, 256, 0, stream>>>(num_part, den_part, out);
}